// Round 3
// baseline (1457.012 us; speedup 1.0000x reference)
//
#include <hip/hip_runtime.h>
#include <hip/hip_fp16.h>

#define TSTEPS 276
#define NBATCH 32768
#define KDIM   4416   // 276*16
#define NPAD   320    // Wfc rows padded (2 n-halves of 160)
#define NOUT   276

typedef _Float16 half8 __attribute__((ext_vector_type(8)));
typedef float    f32x4 __attribute__((ext_vector_type(4)));
typedef float    f32x2 __attribute__((ext_vector_type(2)));

__device__ __forceinline__ float fast_sigmoid(float x) {
    float e = __builtin_amdgcn_exp2f(-1.4426950408889634f * x);
    return __builtin_amdgcn_rcpf(1.0f + e);
}
__device__ __forceinline__ float fast_tanh(float x) {
    float e = __builtin_amdgcn_exp2f(2.885390081777927f * x);
    return 1.0f - 2.0f * __builtin_amdgcn_rcpf(1.0f + e);
}

// ---------------- Kernel 1: bidirectional LSTM (row chunk) ----------------
// 8 lanes per (row, dir); gate pairs (i,f) and (g,o) packed as f32x2 to get
// v_pk_fma_f32. x load software-pipelined one step ahead (breaks the serial
// dependent-load stall). h exchanged via __shfl within the 8-lane group.
__global__ __launch_bounds__(256) void lstm_kernel(
    const float* __restrict__ x,
    const float* __restrict__ Wih_f, const float* __restrict__ Whh_f,
    const float* __restrict__ bih_f, const float* __restrict__ bhh_f,
    const float* __restrict__ Wih_b, const float* __restrict__ Whh_b,
    const float* __restrict__ bih_b, const float* __restrict__ bhh_b,
    int row0, _Float16* __restrict__ Hout)
{
    const int tid = threadIdx.x;
    const int k   = tid & 7;                       // h-index this lane owns
    const int rd  = blockIdx.x * 32 + (tid >> 3);  // chunk-local row-dir id
    const int bl  = rd >> 1;                       // chunk-local row
    const int dir = rd & 1;
    const int bg  = row0 + bl;                     // global row

    const float* Wih = dir ? Wih_b : Wih_f;
    const float* Whh = dir ? Whh_b : Whh_f;
    const float* bih = dir ? bih_b : bih_f;
    const float* bhh = dir ? bhh_b : bhh_f;

    // gate rows: i=k, f=8+k, g=16+k, o=24+k (PyTorch order)
    f32x2 W01[8], W23[8], Wi0_01, Wi1_01, Wi0_23, Wi1_23, bs01, bs23;
    #pragma unroll
    for (int j = 0; j < 8; ++j) {
        W01[j] = f32x2{Whh[(k) * 8 + j],      Whh[(8 + k) * 8 + j]};
        W23[j] = f32x2{Whh[(16 + k) * 8 + j], Whh[(24 + k) * 8 + j]};
    }
    Wi0_01 = f32x2{Wih[(k) * 2 + 0],      Wih[(8 + k) * 2 + 0]};
    Wi1_01 = f32x2{Wih[(k) * 2 + 1],      Wih[(8 + k) * 2 + 1]};
    Wi0_23 = f32x2{Wih[(16 + k) * 2 + 0], Wih[(24 + k) * 2 + 0]};
    Wi1_23 = f32x2{Wih[(16 + k) * 2 + 1], Wih[(24 + k) * 2 + 1]};
    bs01   = f32x2{bih[k] + bhh[k],           bih[8 + k] + bhh[8 + k]};
    bs23   = f32x2{bih[16 + k] + bhh[16 + k], bih[24 + k] + bhh[24 + k]};

    const int laneBase = tid & 56;                 // first lane of my 8-group
    const float2* __restrict__ xrow = (const float2*)(x + (size_t)bg * (TSTEPS * 2));
    _Float16* __restrict__ hrow = Hout + (size_t)bl * KDIM + dir * 8 + k;

    float h = 0.0f, c = 0.0f;
    float2 xv = xrow[dir ? (TSTEPS - 1) : 0];
    for (int s = 0; s < TSTEPS; ++s) {
        const int tau = dir ? (TSTEPS - 1 - s) : s;
        const int s2  = (s + 1 < TSTEPS) ? (s + 1) : s;
        const int tau_n = dir ? (TSTEPS - 1 - s2) : s2;
        float2 xv_n = xrow[tau_n];                 // prefetch next step

        float hv[8];
        #pragma unroll
        for (int j = 0; j < 8; ++j) hv[j] = __shfl(h, laneBase + j, 64);

        f32x2 a01 = bs01 + Wi0_01 * xv.x + Wi1_01 * xv.y;
        f32x2 a23 = bs23 + Wi0_23 * xv.x + Wi1_23 * xv.y;
        #pragma unroll
        for (int j = 0; j < 8; ++j) {
            a01 += W01[j] * hv[j];
            a23 += W23[j] * hv[j];
        }
        const float ig = fast_sigmoid(a01.x);
        const float fg = fast_sigmoid(a01.y);
        const float gg = fast_tanh(a23.x);
        const float og = fast_sigmoid(a23.y);
        c = fmaf(fg, c, ig * gg);
        h = og * fast_tanh(c);

        hrow[tau * 16] = (_Float16)h;
        xv = xv_n;
    }
}

// ---------------- Kernel 2: Wfc fp32 -> fp16, padded to NPAD rows ----------------
__global__ __launch_bounds__(256) void conv_kernel(const float* __restrict__ Wfc,
                                                   _Float16* __restrict__ W2)
{
    int i = blockIdx.x * 256 + threadIdx.x;        // over NPAD*KDIM
    if (i < NPAD * KDIM) {
        int n = i / KDIM;
        W2[i] = (n < NOUT) ? (_Float16)Wfc[i] : (_Float16)0.0f;
    }
}

// ---------------- Kernel 3: out[rows,276] = H[rows,4416] * W2^T + bfc ----------------
// LDS-free: wave tile 16(M) x 160(N) = 10 16x16x32 MFMA tiles; A fragments
// straight from global (each 64B line consumed once), B is L1/L2-resident.
// No barriers anywhere; unroll-2 lets the scheduler pipeline loads over MFMA.
__global__ __launch_bounds__(256) void gemm_kernel(
    const _Float16* __restrict__ H, const _Float16* __restrict__ W2,
    const float* __restrict__ bfc, float* __restrict__ out)
{
    const int tid  = threadIdx.x;
    const int lane = tid & 63;
    const int wid  = tid >> 6;                     // 0..3
    const int mg   = blockIdx.x * 2 + (wid >> 1);  // 16-row group
    const int nh   = wid & 1;                      // n-half (160 cols)
    const int m0   = mg * 16;
    const int n0   = nh * 160;

    const int r  = lane & 15;                      // row/col within tile
    const int kq = lane >> 4;                      // k-quarter (8 halfs)

    const _Float16* Ap = H  + (size_t)(m0 + r) * KDIM + kq * 8;
    const _Float16* Bp = W2 + (size_t)(n0 + r) * KDIM + kq * 8;

    f32x4 acc[10] = {};

    #pragma unroll 2
    for (int k0 = 0; k0 < KDIM; k0 += 32) {
        half8 af = *(const half8*)(Ap + k0);
        half8 bf[10];
        #pragma unroll
        for (int ni = 0; ni < 10; ++ni)
            bf[ni] = *(const half8*)(Bp + (size_t)(ni * 16) * KDIM + k0);
        #pragma unroll
        for (int ni = 0; ni < 10; ++ni)
            acc[ni] = __builtin_amdgcn_mfma_f32_16x16x32_f16(af, bf[ni], acc[ni], 0, 0, 0);
    }

    // C layout (16x16): col = lane&15, row = (lane>>4)*4 + reg
    const int rowb = m0 + (lane >> 4) * 4;
    #pragma unroll
    for (int ni = 0; ni < 10; ++ni) {
        int n = n0 + ni * 16 + r;
        if (n < NOUT) {
            float bv = bfc[n];
            #pragma unroll
            for (int g = 0; g < 4; ++g)
                out[(size_t)(rowb + g) * NOUT + n] = acc[ni][g] + bv;
        }
    }
}

extern "C" void kernel_launch(void* const* d_in, const int* in_sizes, int n_in,
                              void* d_out, int out_size, void* d_ws, size_t ws_size,
                              hipStream_t stream) {
    const float* x     = (const float*)d_in[0];
    const float* Wih_f = (const float*)d_in[1];
    const float* Whh_f = (const float*)d_in[2];
    const float* bih_f = (const float*)d_in[3];
    const float* bhh_f = (const float*)d_in[4];
    const float* Wih_b = (const float*)d_in[5];
    const float* Whh_b = (const float*)d_in[6];
    const float* bih_b = (const float*)d_in[7];
    const float* bhh_b = (const float*)d_in[8];
    const float* Wfc   = (const float*)d_in[9];
    const float* bfc   = (const float*)d_in[10];
    float* out = (float*)d_out;

    // Workspace layout: [W2: NPAD*KDIM fp16][H chunk: chunk*KDIM fp16]
    _Float16* W2 = (_Float16*)d_ws;
    size_t h_off = ((size_t)NPAD * KDIM * 2 + 255) & ~(size_t)255;
    size_t avail = (ws_size > h_off) ? (ws_size - h_off) : 0;
    long maxrows = (long)(avail / ((size_t)KDIM * 2));
    int chunk = (int)((maxrows / 128) * 128);      // keep M multiple of 32
    if (chunk > NBATCH) chunk = NBATCH;
    if (chunk < 128)    chunk = 128;
    _Float16* Hc = (_Float16*)((char*)d_ws + h_off);

    conv_kernel<<<(NPAD * KDIM + 255) / 256, 256, 0, stream>>>(Wfc, W2);

    for (int r0 = 0; r0 < NBATCH; r0 += chunk) {
        int rows = NBATCH - r0; if (rows > chunk) rows = chunk;
        lstm_kernel<<<rows / 16, 256, 0, stream>>>(x, Wih_f, Whh_f, bih_f, bhh_f,
                                                   Wih_b, Whh_b, bih_b, bhh_b,
                                                   r0, Hc);
        gemm_kernel<<<rows / 32, 256, 0, stream>>>(Hc, W2, bfc,
                                                   out + (size_t)r0 * NOUT);
    }
}